// Round 1
// baseline (498.724 us; speedup 1.0000x reference)
//
#include <hip/hip_runtime.h>

// CRF loss: mean_b( logZ(b) - gold(b) )
// B=2048, T=512, K=25 (OUT=23, START=23, STOP=24), NEG=-10000
//
// Mapping: one 64-lane wave per batch element. Lane i (i<25) owns state i and
// keeps transitions[i][0..24] in registers. alpha[j] broadcast via __shfl.
// Gold path score fused into the forward loop (lane tag_t holds the emit).

#define BB 2048
#define TT 512
#define KK 25
#define START_S 23
#define STOP_S 24
#define NEGV (-10000.0f)

static __device__ __forceinline__ float fast_exp2(float x) {
    return __builtin_amdgcn_exp2f(x);
}
static __device__ __forceinline__ float fast_log2(float x) {
    return __builtin_amdgcn_logf(x);
}

__global__ __launch_bounds__(256) void crf_loss_kernel(
    const float* __restrict__ feats,      // [B][T][K]
    const int*   __restrict__ tags,       // [B][T]
    const int*   __restrict__ lengths,    // [B]
    const float* __restrict__ trans,      // [K][K]  (row i = scores into state i)
    float*       __restrict__ out)        // [1]
{
    __shared__ float tlds[KK * KK];
    for (int idx = threadIdx.x; idx < KK * KK; idx += blockDim.x)
        tlds[idx] = trans[idx];
    __syncthreads();

    const int wid  = threadIdx.x >> 6;
    const int lane = threadIdx.x & 63;
    const int b    = blockIdx.x * 4 + wid;

    const int len = lengths[b];                 // guaranteed 1..T
    const float* fb = feats + (size_t)b * TT * KK;
    const int*   tb = tags  + (size_t)b * TT;

    const float LOG2E = 1.4426950408889634f;
    const float LN2   = 0.6931471805599453f;

    // Per-lane transition row (lane i -> row i). Lanes >=25 read row 0 (unused).
    const int rowbase = (lane < KK ? lane : 0) * KK;
    float trow[KK];
    #pragma unroll
    for (int j = 0; j < KK; ++j) trow[j] = tlds[rowbase + j];

    float a = (lane == START_S) ? 0.0f : NEGV;  // alpha[lane]
    float g = 0.0f;                             // gold partial (this lane's hits)
    int tag_prev = START_S;

    // Prefetch t=0
    float fnext   = (lane < KK) ? fb[lane] : 0.0f;
    int   tagnext = tb[0];

    for (int t = 0; t < len; ++t) {
        const float fcur = fnext;
        const int   tagt = tagnext;
        if (t + 1 < len) {
            fnext   = (lane < KK) ? fb[(t + 1) * KK + lane] : 0.0f;
            tagnext = tb[t + 1];
        }

        // v[j] = alpha[j] + trans[i][j]
        float v[KK];
        #pragma unroll
        for (int j = 0; j < KK; ++j)
            v[j] = trow[j] + __shfl(a, j);

        // tree max over v[0..24] (24 fmax ops, ~5 dependent levels)
        float mm[13];
        #pragma unroll
        for (int j = 0; j < 12; ++j) mm[j] = fmaxf(v[2 * j], v[2 * j + 1]);
        mm[12] = v[24];
        #pragma unroll
        for (int j = 0; j < 6; ++j) mm[j] = fmaxf(mm[j], mm[j + 6]);
        mm[0] = fmaxf(mm[0], mm[3]);
        mm[1] = fmaxf(mm[1], mm[4]);
        mm[2] = fmaxf(mm[2], mm[5]);
        mm[0] = fmaxf(mm[0], mm[1]);
        mm[2] = fmaxf(mm[2], mm[12]);
        const float m = fmaxf(mm[0], mm[2]);

        // sum exp(v - m), 4 parallel accumulators
        float s0 = 0.0f, s1 = 0.0f, s2 = 0.0f, s3 = 0.0f;
        #pragma unroll
        for (int j = 0; j < 24; j += 4) {
            s0 += fast_exp2((v[j]     - m) * LOG2E);
            s1 += fast_exp2((v[j + 1] - m) * LOG2E);
            s2 += fast_exp2((v[j + 2] - m) * LOG2E);
            s3 += fast_exp2((v[j + 3] - m) * LOG2E);
        }
        s0 += fast_exp2((v[24] - m) * LOG2E);
        const float s = (s0 + s1) + (s2 + s3);

        const float nxt = m + fast_log2(s) * LN2 + fcur;
        if (lane < KK) a = nxt;

        // gold: emit + transition for the tagged path
        if (lane == tagt) g += fcur + tlds[tagt * KK + tag_prev];
        tag_prev = tagt;
    }

    // fwd_score = logsumexp_i(alpha[i] + trans[STOP][i])
    float w = (lane < KK) ? (a + tlds[STOP_S * KK + lane]) : -3.0e38f;
    float m2 = w;
    #pragma unroll
    for (int off = 32; off; off >>= 1) m2 = fmaxf(m2, __shfl_xor(m2, off));
    float e2 = (lane < KK) ? fast_exp2((w - m2) * LOG2E) : 0.0f;
    #pragma unroll
    for (int off = 32; off; off >>= 1) e2 += __shfl_xor(e2, off);
    const float fwd = m2 + fast_log2(e2) * LN2;

    // gold reduce across lanes (each lane holds its matched-tag partials)
    #pragma unroll
    for (int off = 32; off; off >>= 1) g += __shfl_xor(g, off);

    if (lane == 0) {
        const float gold = g + tlds[STOP_S * KK + tag_prev];  // tag_prev == last_tag
        atomicAdd(out, (fwd - gold) * (1.0f / BB));
    }
}

extern "C" void kernel_launch(void* const* d_in, const int* in_sizes, int n_in,
                              void* d_out, int out_size, void* d_ws, size_t ws_size,
                              hipStream_t stream) {
    const float* feats   = (const float*)d_in[0];
    const int*   tags    = (const int*)d_in[1];
    const int*   lengths = (const int*)d_in[2];
    const float* trans   = (const float*)d_in[3];
    float* out = (float*)d_out;

    hipMemsetAsync(out, 0, sizeof(float), stream);
    crf_loss_kernel<<<BB / 4, 256, 0, stream>>>(feats, tags, lengths, trans, out);
}

// Round 5
// 364.048 us; speedup vs baseline: 1.3699x; 1.3699x over previous
//
#include <hip/hip_runtime.h>

// CRF loss: mean_b( logZ(b) - gold(b) )   B=2048, T=512, K=25
// Linear-domain forward with exact pow2 rescale; 2 batches per wave
// (lanes 0-24 = batch 2p, lanes 32-56 = batch 2p+1), ds_swizzle broadcast.

#define BB 2048
#define TT 512
#define KK 25
#define START_S 23
#define STOP_S 24

#define LOG2E 1.4426950408889634f
#define LN2   0.6931471805599453f

static __device__ __forceinline__ float fexp2(float x) { return __builtin_amdgcn_exp2f(x); }
static __device__ __forceinline__ float flog2(float x) { return __builtin_amdgcn_logf(x); }

// matvec: nxt = sum_j Mrow[j] * A_bcast(j), broadcast within each 32-lane half
static __device__ __forceinline__ float matvec25(const float* Mrow, float A) {
    const int ai = __float_as_int(A);
    float a0 = 0.f, a1 = 0.f, a2 = 0.f, a3 = 0.f;
#define FJ(J, ACC) ACC = fmaf(Mrow[J], __int_as_float(__builtin_amdgcn_ds_swizzle(ai, ((J) << 5))), ACC);
    FJ(0, a0)  FJ(1, a1)  FJ(2, a2)  FJ(3, a3)
    FJ(4, a0)  FJ(5, a1)  FJ(6, a2)  FJ(7, a3)
    FJ(8, a0)  FJ(9, a1)  FJ(10, a2) FJ(11, a3)
    FJ(12, a0) FJ(13, a1) FJ(14, a2) FJ(15, a3)
    FJ(16, a0) FJ(17, a1) FJ(18, a2) FJ(19, a3)
    FJ(20, a0) FJ(21, a1) FJ(22, a2) FJ(23, a3)
    FJ(24, a0)
#undef FJ
    return (a0 + a1) + (a2 + a3);
}

static __device__ __forceinline__ void crf_step(
    float& A, float& g, int& tag_prev,
    const float* Mrow, const float* tlds,
    float fcur, int tagt, bool act, bool inK, int sl)
{
    const float s   = matvec25(Mrow, A);
    const float nxt = s * fexp2(fcur * LOG2E);
    A = (act && inK) ? nxt : A;
    if (act && sl == tagt) g += fcur + tlds[tagt * KK + tag_prev];
    if (act) tag_prev = tagt;
}

__global__ __launch_bounds__(64) void crf_loss_kernel(
    const float* __restrict__ feats,      // [B][T][K]
    const int*   __restrict__ tags,       // [B][T]
    const int*   __restrict__ lengths,    // [B]
    const float* __restrict__ trans,      // [K][K]
    float*       __restrict__ out)        // [1]
{
    __shared__ float tlds[KK * KK];

    const int lane = threadIdx.x & 63;
    for (int i = threadIdx.x; i < KK * KK; i += 64) tlds[i] = trans[i];
    __syncthreads();

    const int pair = blockIdx.x;
    const int half = lane >> 5;
    const int sl   = lane & 31;
    const int b    = pair * 2 + half;

    const int len  = lengths[b];                       // this half's length
    const int lmax = max(lengths[pair * 2], lengths[pair * 2 + 1]);

    const float* fb = feats + (size_t)b * TT * KK;
    const int*   tb = tags  + (size_t)b * TT;

    const bool inK = sl < KK;
    const int rowbase = (inK ? sl : 0) * KK;
    float Mrow[KK];
    #pragma unroll
    for (int j = 0; j < KK; ++j) Mrow[j] = fexp2(tlds[rowbase + j] * LOG2E);

    float A = (sl == START_S) ? 1.0f : 0.0f;   // linear alpha, scale 2^c2
    int   c2 = 0;
    float g  = 0.0f;
    int   tag_prev = START_S;

    // preload group 0 (rows 0..3 always in-bounds: T>=4)
    float cf0 = inK ? fb[0 * KK + sl] : 0.f;
    float cf1 = inK ? fb[1 * KK + sl] : 0.f;
    float cf2 = inK ? fb[2 * KK + sl] : 0.f;
    float cf3 = inK ? fb[3 * KK + sl] : 0.f;
    int4  ct  = *(const int4*)tb;

    const int ngroups = (lmax + 3) >> 2;
    for (int gi = 0; gi < ngroups; ++gi) {
        const int base = gi * 4;
        const int nb   = base + 4;
        // prefetch next group (clamped; dead work beyond lmax is masked)
        const float nf0 = inK ? fb[min(nb + 0, TT - 1) * KK + sl] : 0.f;
        const float nf1 = inK ? fb[min(nb + 1, TT - 1) * KK + sl] : 0.f;
        const float nf2 = inK ? fb[min(nb + 2, TT - 1) * KK + sl] : 0.f;
        const float nf3 = inK ? fb[min(nb + 3, TT - 1) * KK + sl] : 0.f;
        const int4  nt  = *(const int4*)(tb + min(nb, TT - 4));

        crf_step(A, g, tag_prev, Mrow, tlds, cf0, ct.x, base + 0 < len, inK, sl);
        crf_step(A, g, tag_prev, Mrow, tlds, cf1, ct.y, base + 1 < len, inK, sl);
        crf_step(A, g, tag_prev, Mrow, tlds, cf2, ct.z, base + 2 < len, inK, sl);
        crf_step(A, g, tag_prev, Mrow, tlds, cf3, ct.w, base + 3 < len, inK, sl);

        // exact pow2 rescale (per half): A_max -> [1,2)
        float m = A;
        m = fmaxf(m, __shfl_xor(m, 16));
        m = fmaxf(m, __shfl_xor(m, 8));
        m = fmaxf(m, __shfl_xor(m, 4));
        m = fmaxf(m, __shfl_xor(m, 2));
        m = fmaxf(m, __shfl_xor(m, 1));
        const int e = (int)(__float_as_uint(m) >> 23) - 127;
        A *= __uint_as_float((unsigned)(127 - e) << 23);   // exact *2^-e
        c2 += e;

        cf0 = nf0; cf1 = nf1; cf2 = nf2; cf3 = nf3; ct = nt;
    }

    // fwd = log( sum_i A_i * exp(T[STOP][i]) ) + c2*ln2
    const float es = inK ? fexp2(tlds[STOP_S * KK + sl] * LOG2E) : 0.f;
    float w = A * es;
    w += __shfl_xor(w, 16);
    w += __shfl_xor(w, 8);
    w += __shfl_xor(w, 4);
    w += __shfl_xor(w, 2);
    w += __shfl_xor(w, 1);
    const float fwd = (flog2(w) + (float)c2) * LN2;

    // gold reduce within half
    g += __shfl_xor(g, 16);
    g += __shfl_xor(g, 8);
    g += __shfl_xor(g, 4);
    g += __shfl_xor(g, 2);
    g += __shfl_xor(g, 1);

    if (sl == 0) {
        const float gold = g + tlds[STOP_S * KK + tag_prev];
        atomicAdd(out, (fwd - gold) * (1.0f / BB));
    }
}

extern "C" void kernel_launch(void* const* d_in, const int* in_sizes, int n_in,
                              void* d_out, int out_size, void* d_ws, size_t ws_size,
                              hipStream_t stream) {
    const float* feats   = (const float*)d_in[0];
    const int*   tags    = (const int*)d_in[1];
    const int*   lengths = (const int*)d_in[2];
    const float* trans   = (const float*)d_in[3];
    float* out = (float*)d_out;

    hipMemsetAsync(out, 0, sizeof(float), stream);
    crf_loss_kernel<<<BB / 2, 64, 0, stream>>>(feats, tags, lengths, trans, out);
}

// Round 8
// 267.704 us; speedup vs baseline: 1.8630x; 1.3599x over previous
//
#include <hip/hip_runtime.h>

// CRF loss: mean_b( logZ(b) - gold(b) )   B=2048, T=512, K=25
// Linear-domain forward, exact pow2 rescale every 4 steps, 2 batches/wave
// (lanes 0-24 = batch 2p, lanes 32-56 = batch 2p+1; ds_swizzle broadcast).
// R7: fix R6 compile error — ds_swizzle offset must be a literal constant,
// so the 25 broadcasts are macro-expanded with constant offsets.
// __launch_bounds__(64,1) frees VGPRs; 8-step-deep prefetch; emission exp2
// hoisted off the serial alpha chain.

#define BB 2048
#define TT 512
#define KK 25
#define START_S 23
#define STOP_S 24

#define LOG2E 1.4426950408889634f
#define LN2   0.6931471805599453f

static __device__ __forceinline__ float fexp2(float x) { return __builtin_amdgcn_exp2f(x); }
static __device__ __forceinline__ float flog2(float x) { return __builtin_amdgcn_logf(x); }

static __device__ __forceinline__ void crf_step(
    float& A, float& g, int& tag_prev,
    const float* Mrow, const float* tlds,
    float fcur, float ef, int tagt, bool act, bool inK, int sl)
{
    const int ai = __float_as_int(A);
    float br[KK];
    // batch-issue all 25 swizzle broadcasts (constant offsets required)
#define BC(J) br[J] = __int_as_float(__builtin_amdgcn_ds_swizzle(ai, ((J) << 5)));
    BC(0)  BC(1)  BC(2)  BC(3)  BC(4)
    BC(5)  BC(6)  BC(7)  BC(8)  BC(9)
    BC(10) BC(11) BC(12) BC(13) BC(14)
    BC(15) BC(16) BC(17) BC(18) BC(19)
    BC(20) BC(21) BC(22) BC(23) BC(24)
#undef BC

    float a0 = 0.f, a1 = 0.f, a2 = 0.f, a3 = 0.f;
    #pragma unroll
    for (int j = 0; j < 24; j += 4) {
        a0 = fmaf(Mrow[j],     br[j],     a0);
        a1 = fmaf(Mrow[j + 1], br[j + 1], a1);
        a2 = fmaf(Mrow[j + 2], br[j + 2], a2);
        a3 = fmaf(Mrow[j + 3], br[j + 3], a3);
    }
    a0 = fmaf(Mrow[24], br[24], a0);

    const float nxt = ((a0 + a1) + (a2 + a3)) * ef;      // ef precomputed off-chain
    A = (act && inK) ? nxt : A;
    if (act && sl == tagt) g += fcur + tlds[tagt * KK + tag_prev];
    if (act) tag_prev = tagt;
}

__global__ __launch_bounds__(64, 1) void crf_loss_kernel(
    const float* __restrict__ feats,      // [B][T][K]
    const int*   __restrict__ tags,       // [B][T]
    const int*   __restrict__ lengths,    // [B]
    const float* __restrict__ trans,      // [K][K]
    float*       __restrict__ out)        // [1]
{
    __shared__ float tlds[KK * KK];

    const int lane = threadIdx.x & 63;
    for (int i = threadIdx.x; i < KK * KK; i += 64) tlds[i] = trans[i];
    __syncthreads();

    const int pair = blockIdx.x;
    const int half = lane >> 5;
    const int sl   = lane & 31;
    const int b    = pair * 2 + half;

    const int len  = lengths[b];
    const int lmax = max(lengths[pair * 2], lengths[pair * 2 + 1]);

    const float* fb = feats + (size_t)b * TT * KK;
    const int*   tb = tags  + (size_t)b * TT;

    const bool inK = sl < KK;
    const int rowbase = (inK ? sl : 0) * KK;
    float Mrow[KK];
    #pragma unroll
    for (int j = 0; j < KK; ++j) Mrow[j] = fexp2(tlds[rowbase + j] * LOG2E);

    float A = (sl == START_S) ? 1.0f : 0.0f;   // linear alpha, scale 2^c2
    int   c2 = 0;
    float g  = 0.0f;
    int   tag_prev = START_S;

    const int fidx = inK ? sl : 0;

    // preload groups 0 and 1 (rows 0..7 always in-bounds: T=512)
    float a00 = fb[0 * KK + fidx], a01 = fb[1 * KK + fidx];
    float a02 = fb[2 * KK + fidx], a03 = fb[3 * KK + fidx];
    int4  t0  = *(const int4*)tb;
    float a10 = fb[4 * KK + fidx], a11 = fb[5 * KK + fidx];
    float a12 = fb[6 * KK + fidx], a13 = fb[7 * KK + fidx];
    int4  t1  = *(const int4*)(tb + 4);

    const int ngroups = (lmax + 3) >> 2;

    #define RESCALE()                                                        \
    {                                                                        \
        float m = A;                                                         \
        m = fmaxf(m, __shfl_xor(m, 16));                                     \
        m = fmaxf(m, __shfl_xor(m, 8));                                      \
        m = fmaxf(m, __shfl_xor(m, 4));                                      \
        m = fmaxf(m, __shfl_xor(m, 2));                                      \
        m = fmaxf(m, __shfl_xor(m, 1));                                      \
        const int e = (int)(__float_as_uint(m) >> 23) - 127;                 \
        A *= __uint_as_float((unsigned)(127 - e) << 23);                     \
        c2 += e;                                                             \
    }

    #define DO_GROUP(BASE, F0, F1, F2, F3, T4)                               \
    {                                                                        \
        const float e0 = fexp2(F0 * LOG2E);                                  \
        const float e1 = fexp2(F1 * LOG2E);                                  \
        const float e2 = fexp2(F2 * LOG2E);                                  \
        const float e3 = fexp2(F3 * LOG2E);                                  \
        crf_step(A, g, tag_prev, Mrow, tlds, F0, e0, T4.x, (BASE) + 0 < len, inK, sl); \
        crf_step(A, g, tag_prev, Mrow, tlds, F1, e1, T4.y, (BASE) + 1 < len, inK, sl); \
        crf_step(A, g, tag_prev, Mrow, tlds, F2, e2, T4.z, (BASE) + 2 < len, inK, sl); \
        crf_step(A, g, tag_prev, Mrow, tlds, F3, e3, T4.w, (BASE) + 3 < len, inK, sl); \
        RESCALE();                                                           \
    }

    for (int gi = 0; gi < ngroups; gi += 2) {
        // issue loads for groups gi+2 and gi+3 (8 steps ahead; clamped rows,
        // dead values are masked by (BASE+k < len))
        const int p2 = min((gi + 2) * 4, TT - 4);
        const int p3 = min((gi + 3) * 4, TT - 4);
        const float b00 = fb[(p2 + 0) * KK + fidx];
        const float b01 = fb[(p2 + 1) * KK + fidx];
        const float b02 = fb[(p2 + 2) * KK + fidx];
        const float b03 = fb[(p2 + 3) * KK + fidx];
        const int4  u2  = *(const int4*)(tb + p2);
        const float b10 = fb[(p3 + 0) * KK + fidx];
        const float b11 = fb[(p3 + 1) * KK + fidx];
        const float b12 = fb[(p3 + 2) * KK + fidx];
        const float b13 = fb[(p3 + 3) * KK + fidx];
        const int4  u3  = *(const int4*)(tb + p3);

        DO_GROUP(gi * 4,     a00, a01, a02, a03, t0);
        DO_GROUP(gi * 4 + 4, a10, a11, a12, a13, t1);

        a00 = b00; a01 = b01; a02 = b02; a03 = b03; t0 = u2;
        a10 = b10; a11 = b11; a12 = b12; a13 = b13; t1 = u3;
    }

    #undef DO_GROUP
    #undef RESCALE

    // fwd = log( sum_i A_i * exp(T[STOP][i]) ) + c2*ln2
    const float es = inK ? fexp2(tlds[STOP_S * KK + sl] * LOG2E) : 0.f;
    float w = (inK ? A : 0.f) * es;
    w += __shfl_xor(w, 16);
    w += __shfl_xor(w, 8);
    w += __shfl_xor(w, 4);
    w += __shfl_xor(w, 2);
    w += __shfl_xor(w, 1);
    const float fwd = (flog2(w) + (float)c2) * LN2;

    // gold reduce within half
    g += __shfl_xor(g, 16);
    g += __shfl_xor(g, 8);
    g += __shfl_xor(g, 4);
    g += __shfl_xor(g, 2);
    g += __shfl_xor(g, 1);

    if (sl == 0) {
        const float gold = g + tlds[STOP_S * KK + tag_prev];
        atomicAdd(out, (fwd - gold) * (1.0f / BB));
    }
}

extern "C" void kernel_launch(void* const* d_in, const int* in_sizes, int n_in,
                              void* d_out, int out_size, void* d_ws, size_t ws_size,
                              hipStream_t stream) {
    const float* feats   = (const float*)d_in[0];
    const int*   tags    = (const int*)d_in[1];
    const int*   lengths = (const int*)d_in[2];
    const float* trans   = (const float*)d_in[3];
    float* out = (float*)d_out;

    (void)hipMemsetAsync(out, 0, sizeof(float), stream);
    crf_loss_kernel<<<BB / 2, 64, 0, stream>>>(feats, tags, lengths, trans, out);
}

// Round 9
// 256.212 us; speedup vs baseline: 1.9465x; 1.0449x over previous
//
#include <hip/hip_runtime.h>

// CRF loss: mean_b( logZ(b) - gold(b) )   B=2048, T=512, K=25
// R9: SGPR-alpha recurrence. One batch per wave (2048 waves = 2/SIMD).
// Lane i holds M row i (exp of transitions); alpha[0..24] live in SGPRs via
// v_readlane; matvec = 25 v_fma with SGPR operand. No DS ops on the chain.
// Exact-length execution (no masking); SALU rescale folded into next e0.

#define BB 2048
#define TT 512
#define KK 25
#define START_S 23
#define STOP_S 24

#define LOG2E 1.4426950408889634f
#define LN2   0.6931471805599453f

static __device__ __forceinline__ float fexp2(float x) { return __builtin_amdgcn_exp2f(x); }
static __device__ __forceinline__ float flog2(float x) { return __builtin_amdgcn_logf(x); }

__global__ __launch_bounds__(64) void crf_loss_kernel(
    const float* __restrict__ feats,      // [B][T][K]
    const int*   __restrict__ tags,       // [B][T]
    const int*   __restrict__ lengths,    // [B]
    const float* __restrict__ trans,      // [K][K]
    float*       __restrict__ out)        // [1]
{
    __shared__ float tlds[KK * KK];

    const int lane = threadIdx.x;
    for (int i = lane; i < KK * KK; i += 64) tlds[i] = trans[i];
    __syncthreads();

    const int b   = blockIdx.x;
    const int len = lengths[b];                         // 1..T

    const float* fb = feats + (size_t)b * TT * KK;
    const int*   tb = tags  + (size_t)b * TT;

    const bool inK  = lane < KK;
    const int  fidx = inK ? lane : 0;

    // lane i holds exp(T[i][j]) for j=0..24
    const int rowbase = fidx * KK;
    float Mrow[KK];
    #pragma unroll
    for (int j = 0; j < KK; ++j) Mrow[j] = fexp2(tlds[rowbase + j] * LOG2E);

    // alpha in SGPRs (uniform): init = indicator(START)
    float al[KK];
    #pragma unroll
    for (int j = 0; j < KK; ++j) al[j] = (j == START_S) ? 1.0f : 0.0f;

    float A = 0.0f;          // per-lane alpha (lane i = alpha_i), set by STEP
    float scale = 1.0f;      // pending pow2 rescale (invariant: true = al*scale*2^c2)
    int   c2 = 0;
    float g  = 0.0f;
    int   tag_prev = START_S;

    // refresh SGPR alphas from per-lane A (literal lane indices required)
#define RL(J) al[J] = __int_as_float(__builtin_amdgcn_readlane(__float_as_int(A), J));
#define RL_ALL() \
    RL(0)  RL(1)  RL(2)  RL(3)  RL(4)  \
    RL(5)  RL(6)  RL(7)  RL(8)  RL(9)  \
    RL(10) RL(11) RL(12) RL(13) RL(14) \
    RL(15) RL(16) RL(17) RL(18) RL(19) \
    RL(20) RL(21) RL(22) RL(23) RL(24)

#define STEP(F, EF, TAGT)                                                    \
    {                                                                        \
        float a0 = 0.f, a1 = 0.f, a2 = 0.f, a3 = 0.f;                        \
        _Pragma("unroll")                                                    \
        for (int j = 0; j < 24; j += 4) {                                    \
            a0 = fmaf(Mrow[j],     al[j],     a0);                           \
            a1 = fmaf(Mrow[j + 1], al[j + 1], a1);                           \
            a2 = fmaf(Mrow[j + 2], al[j + 2], a2);                           \
            a3 = fmaf(Mrow[j + 3], al[j + 3], a3);                           \
        }                                                                    \
        a0 = fmaf(Mrow[24], al[24], a0);                                     \
        A = ((a0 + a1) + (a2 + a3)) * (EF);                                  \
        RL_ALL();                                                            \
        if (lane == (TAGT)) g += (F) + tlds[(TAGT) * KK + tag_prev];         \
        tag_prev = (TAGT);                                                   \
    }

    // group of 4 steps + SALU rescale; pending scale folds into e0 only
#define DO_GROUP(F0, F1, F2, F3, T4)                                         \
    {                                                                        \
        const float e0 = fexp2((F0) * LOG2E) * scale;                        \
        const float e1 = fexp2((F1) * LOG2E);                                \
        const float e2 = fexp2((F2) * LOG2E);                                \
        const float e3 = fexp2((F3) * LOG2E);                                \
        STEP(F0, e0, T4.x)                                                   \
        STEP(F1, e1, T4.y)                                                   \
        STEP(F2, e2, T4.z)                                                   \
        STEP(F3, e3, T4.w)                                                   \
        unsigned mx = 0u;                                                    \
        _Pragma("unroll")                                                    \
        for (int j = 0; j < KK; ++j)                                         \
            mx = max(mx, (unsigned)__float_as_int(al[j]));                   \
        const int e = (int)(mx >> 23) - 127;                                 \
        scale = __uint_as_float((unsigned)(127 - e) << 23);                  \
        c2 += e;                                                             \
    }

    // preload groups 0 and 1 (rows 0..7 always in-bounds: T=512)
    float a00 = fb[0 * KK + fidx], a01 = fb[1 * KK + fidx];
    float a02 = fb[2 * KK + fidx], a03 = fb[3 * KK + fidx];
    int4  t0  = *(const int4*)tb;
    float a10 = fb[4 * KK + fidx], a11 = fb[5 * KK + fidx];
    float a12 = fb[6 * KK + fidx], a13 = fb[7 * KK + fidx];
    int4  t1  = *(const int4*)(tb + 4);

    const int ngroups = len >> 2;
    const int npairs  = ngroups >> 1;

    for (int p = 0; p < npairs; ++p) {
        const int p2 = min((p * 2 + 2) * 4, TT - 4);
        const int p3 = min((p * 2 + 3) * 4, TT - 4);
        const float b00 = fb[(p2 + 0) * KK + fidx];
        const float b01 = fb[(p2 + 1) * KK + fidx];
        const float b02 = fb[(p2 + 2) * KK + fidx];
        const float b03 = fb[(p2 + 3) * KK + fidx];
        const int4  u2  = *(const int4*)(tb + p2);
        const float b10 = fb[(p3 + 0) * KK + fidx];
        const float b11 = fb[(p3 + 1) * KK + fidx];
        const float b12 = fb[(p3 + 2) * KK + fidx];
        const float b13 = fb[(p3 + 3) * KK + fidx];
        const int4  u3  = *(const int4*)(tb + p3);

        DO_GROUP(a00, a01, a02, a03, t0);
        DO_GROUP(a10, a11, a12, a13, t1);

        a00 = b00; a01 = b01; a02 = b02; a03 = b03; t0 = u2;
        a10 = b10; a11 = b11; a12 = b12; a13 = b13; t1 = u3;
    }
    if (ngroups & 1) {
        DO_GROUP(a00, a01, a02, a03, t0);
    }

    // remainder 0..3 steps (direct loads; fold pending scale on first)
    const int base = len & ~3;
    const int rem  = len & 3;
    for (int k = 0; k < rem; ++k) {
        const float f  = fb[(base + k) * KK + fidx];
        const int   tg = tb[base + k];
        const float ef = fexp2(f * LOG2E) * scale;
        scale = 1.0f;
        STEP(f, ef, tg)
    }

#undef DO_GROUP
#undef STEP
#undef RL_ALL
#undef RL

    // fwd = log2( sum_i al_i*scale * exp(T[STOP][i]) ) + c2, in nats
    const float es = inK ? fexp2(tlds[STOP_S * KK + lane] * LOG2E) : 0.f;
    float w = inK ? (A * es) : 0.f;
    w += __shfl_xor(w, 32);
    w += __shfl_xor(w, 16);
    w += __shfl_xor(w, 8);
    w += __shfl_xor(w, 4);
    w += __shfl_xor(w, 2);
    w += __shfl_xor(w, 1);
    const float fwd = (flog2(w * scale) + (float)c2) * LN2;

    // gold reduce across all 64 lanes
    g += __shfl_xor(g, 32);
    g += __shfl_xor(g, 16);
    g += __shfl_xor(g, 8);
    g += __shfl_xor(g, 4);
    g += __shfl_xor(g, 2);
    g += __shfl_xor(g, 1);

    if (lane == 0) {
        const float gold = g + tlds[STOP_S * KK + tag_prev];
        atomicAdd(out, (fwd - gold) * (1.0f / BB));
    }
}

extern "C" void kernel_launch(void* const* d_in, const int* in_sizes, int n_in,
                              void* d_out, int out_size, void* d_ws, size_t ws_size,
                              hipStream_t stream) {
    const float* feats   = (const float*)d_in[0];
    const int*   tags    = (const int*)d_in[1];
    const int*   lengths = (const int*)d_in[2];
    const float* trans   = (const float*)d_in[3];
    float* out = (float*)d_out;

    (void)hipMemsetAsync(out, 0, sizeof(float), stream);
    crf_loss_kernel<<<BB, 64, 0, stream>>>(feats, tags, lengths, trans, out);
}